// Round 9
// baseline (212.860 us; speedup 1.0000x reference)
//
#include <hip/hip_runtime.h>
#include <math.h>

#define D_GNN 256
#define ATTN  64
#define KNEI  16
#define NROWS 65536
#define NNODES 100000

constexpr float EPSV  = 1e-6f;
constexpr float SCALE = 0.125f;   // 64^-0.5

typedef __attribute__((ext_vector_type(8))) short bf16x8;
typedef __attribute__((ext_vector_type(4))) float f32x4;

__device__ __forceinline__ unsigned short f2bf(float f) {
    union { float f; unsigned u; } v; v.f = f;
    return (unsigned short)((v.u + 0x7FFFu + ((v.u >> 16) & 1u)) >> 16);
}
__device__ __forceinline__ float bf2f(unsigned short h) {
    union { unsigned u; float f; } v; v.u = ((unsigned)h) << 16;
    return v.f;
}

typedef __attribute__((address_space(3))) short lds_short;
typedef __attribute__((address_space(1))) const short gm_short;
__device__ __forceinline__ void gload16(const unsigned short* g, short* l) {
    __builtin_amdgcn_global_load_lds((gm_short*)g, (lds_short*)l, 16, 0, 0);
}

// ---------------------------------------------------------------------------
// prep (merged): blocks [0,25000): allE fp32->bf16; [25000,25256): Mt row;
// [25256,25768): WgT column.
// ---------------------------------------------------------------------------
#define CONV_BLOCKS (NNODES * D_GNN / 1024)   // 25000
__global__ __launch_bounds__(256) void prep(const float* __restrict__ allE,
                                            unsigned short* __restrict__ allEbf,
                                            const float* __restrict__ Wq,
                                            const float* __restrict__ Wk,
                                            unsigned short* __restrict__ Mt,
                                            const float* __restrict__ Wg,
                                            unsigned short* __restrict__ WgT) {
    __shared__ float wq[ATTN];
    int bid = blockIdx.x;
    int j   = threadIdx.x;
    if (bid < CONV_BLOCKS) {
        size_t i = (size_t)bid * 256 + j;
        float4 v = ((const float4*)allE)[i];
        short4 o;
        o.x = (short)f2bf(v.x); o.y = (short)f2bf(v.y);
        o.z = (short)f2bf(v.z); o.w = (short)f2bf(v.w);
        ((short4*)allEbf)[i] = o;
    } else if (bid < CONV_BLOCKS + D_GNN) {
        int i = bid - CONV_BLOCKS;
        if (j < ATTN) wq[j] = Wq[i * ATTN + j];
        __syncthreads();
        float s = 0.f;
#pragma unroll
        for (int a = 0; a < ATTN; ++a) s = fmaf(wq[a], Wk[j * ATTN + a], s);
        Mt[j * D_GNN + i] = f2bf(s);
    } else {
        int k = bid - CONV_BLOCKS - D_GNN;    // 0..511
        WgT[j * 512 + k] = f2bf(Wg[k * D_GNN + j]);
    }
}

// ---------------------------------------------------------------------------
// Fused: Cbf = bf16(C32) (side product) and P = Cbf @ Mt^T -> Pbf bf16.
// 128x256 tile, BK=64, 512 threads = 8 waves (2x4), wave tile 64x64.
// ---------------------------------------------------------------------------
__global__ __launch_bounds__(512) void gemm_P_fused(const float* __restrict__ C32,
                                                    const unsigned short* __restrict__ Mt,
                                                    unsigned short* __restrict__ Cbf,
                                                    unsigned short* __restrict__ Pbf) {
    __shared__ short As[128 * 64];   // 16 KB
    __shared__ short Bs[256 * 64];   // 32 KB
    const int tid  = threadIdx.x;
    const int lane = tid & 63;
    const int wid  = tid >> 6;
    const int wr   = wid >> 2, wc = wid & 3;
    const int l15  = lane & 15, lg = lane >> 4;
    const int brow = blockIdx.x * 128;

    f32x4 acc[4][4] = {};

    for (int k0 = 0; k0 < D_GNN; k0 += 64) {
#pragma unroll
        for (int is = 0; is < 4; ++is) {
            int off  = is * 8192 + tid * 16;
            int row  = off >> 7;
            int cs   = (off & 127) >> 1;
            int lofs = is * 4096 + wid * 512;
            gload16(Mt + (size_t)row * D_GNN + k0 + cs, Bs + lofs);
        }
#pragma unroll
        for (int is = 0; is < 2; ++is) {
            int offsh = is * 4096 + tid * 8;
            int row   = offsh >> 6;
            int col   = offsh & 63;
            size_t gp = (size_t)(brow + row) * D_GNN + k0 + col;
            float4 v0 = *(const float4*)(C32 + gp);
            float4 v1 = *(const float4*)(C32 + gp + 4);
            bf16x8 h;
            h[0] = (short)f2bf(v0.x); h[1] = (short)f2bf(v0.y);
            h[2] = (short)f2bf(v0.z); h[3] = (short)f2bf(v0.w);
            h[4] = (short)f2bf(v1.x); h[5] = (short)f2bf(v1.y);
            h[6] = (short)f2bf(v1.z); h[7] = (short)f2bf(v1.w);
            *(bf16x8*)&As[offsh] = h;
            *(bf16x8*)(Cbf + gp) = h;
        }
        __syncthreads();
#pragma unroll
        for (int kk = 0; kk < 64; kk += 32) {
            bf16x8 af[4], bq[4];
#pragma unroll
            for (int m = 0; m < 4; ++m)
                af[m] = *(const bf16x8*)&As[(wr * 64 + m * 16 + l15) * 64 + kk + lg * 8];
#pragma unroll
            for (int n = 0; n < 4; ++n)
                bq[n] = *(const bf16x8*)&Bs[(wc * 64 + n * 16 + l15) * 64 + kk + lg * 8];
#pragma unroll
            for (int m = 0; m < 4; ++m)
#pragma unroll
                for (int n = 0; n < 4; ++n)
                    acc[m][n] = __builtin_amdgcn_mfma_f32_16x16x32_bf16(af[m], bq[n], acc[m][n], 0, 0, 0);
        }
        __syncthreads();
    }
#pragma unroll
    for (int m = 0; m < 4; ++m) {
        int row0 = brow + wr * 64 + m * 16 + lg * 4;
#pragma unroll
        for (int n = 0; n < 4; ++n) {
            int col = wc * 64 + n * 16 + l15;
#pragma unroll
            for (int r = 0; r < 4; ++r)
                Pbf[(size_t)(row0 + r) * D_GNN + col] = f2bf(acc[m][n][r]);
        }
    }
}

// ---------------------------------------------------------------------------
// gather(LDS-staged) + scores + softmax + weighted sum, bf16. (unchanged R7)
// ---------------------------------------------------------------------------
__global__ __launch_bounds__(256) void gather_attn(unsigned short* __restrict__ PW,
                                                   const unsigned short* __restrict__ allEbf,
                                                   const int* __restrict__ nidx,
                                                   const float* __restrict__ nw) {
    __shared__ short stage[4][KNEI * 512];   // 16KB per wave, 64KB total

    int lane = threadIdx.x & 63;
    int wid  = threadIdx.x >> 6;
    int half = lane >> 5;
    int hl   = lane & 31;
    int b    = blockIdx.x * 8 + wid * 2 + half;

#pragma unroll
    for (int t = 0; t < KNEI; ++t) {
        int idx = nidx[b * KNEI + t];
        gload16(allEbf + (size_t)idx * D_GNN + hl * 8, &stage[wid][t * 512]);
    }

    bf16x8 pq = ((const bf16x8*)(PW + (size_t)b * D_GNN))[hl];
    float p[8];
#pragma unroll
    for (int j = 0; j < 8; ++j) p[j] = bf2f((unsigned short)pq[j]);

    __syncthreads();

    float sc[KNEI];
#pragma unroll
    for (int k = 0; k < KNEI; ++k) {
        bf16x8 v = *(const bf16x8*)&stage[wid][k * 512 + half * 256 + hl * 8];
        float s = 0.f;
#pragma unroll
        for (int j = 0; j < 8; ++j) s = fmaf(bf2f((unsigned short)v[j]), p[j], s);
        sc[k] = s;
    }

    float t8[8];
#pragma unroll
    for (int j = 0; j < 8; ++j) {
        float send = (hl & 16) ? sc[j] : sc[j + 8];
        float keep = (hl & 16) ? sc[j + 8] : sc[j];
        t8[j] = keep + __shfl_xor(send, 16);
    }
    float t4[4];
#pragma unroll
    for (int j = 0; j < 4; ++j) {
        float send = (hl & 1) ? t8[j] : t8[j + 4];
        float keep = (hl & 1) ? t8[j + 4] : t8[j];
        t4[j] = keep + __shfl_xor(send, 1);
    }
    float t2[2];
#pragma unroll
    for (int j = 0; j < 2; ++j) {
        float send = (hl & 2) ? t4[j] : t4[j + 2];
        float keep = (hl & 2) ? t4[j + 2] : t4[j];
        t2[j] = keep + __shfl_xor(send, 2);
    }
    float s1;
    {
        float send = (hl & 4) ? t2[0] : t2[1];
        float keep = (hl & 4) ? t2[1] : t2[0];
        s1 = keep + __shfl_xor(send, 4);
    }
    s1 += __shfl_xor(s1, 8);
    int kidx = ((hl >> 4) & 1) * 8 + (hl & 1) * 4 + ((hl >> 1) & 1) * 2 + ((hl >> 2) & 1);

    float w = nw[b * KNEI + kidx];
    float s = (w < EPSV) ? -INFINITY : fmaf(s1, SCALE, logf(w));

    float mx = s;
    mx = fmaxf(mx, __shfl_xor(mx, 16));
    mx = fmaxf(mx, __shfl_xor(mx, 1));
    mx = fmaxf(mx, __shfl_xor(mx, 2));
    mx = fmaxf(mx, __shfl_xor(mx, 4));
    float e = (mx > -INFINITY) ? expf(s - mx) : 0.f;
    float den = e;
    den += __shfl_xor(den, 16);
    den += __shfl_xor(den, 1);
    den += __shfl_xor(den, 2);
    den += __shfl_xor(den, 4);
    float a = (mx > -INFINITY) ? e / den : 0.f;

    float acc[8] = {};
#pragma unroll
    for (int k = 0; k < KNEI; ++k) {
        int sl = (((k >> 3) & 1) << 4) | ((k >> 2) & 1) | (((k >> 1) & 1) << 1) | ((k & 1) << 2);
        float ak = __shfl(a, sl, 32);
        bf16x8 v = *(const bf16x8*)&stage[wid][k * 512 + half * 256 + hl * 8];
#pragma unroll
        for (int j = 0; j < 8; ++j)
            acc[j] = fmaf(ak, bf2f((unsigned short)v[j]), acc[j]);
    }

    bf16x8 o;
#pragma unroll
    for (int j = 0; j < 8; ++j) o[j] = (short)f2bf(acc[j]);
    ((bf16x8*)(PW + (size_t)b * D_GNN))[hl] = o;
}

// ---------------------------------------------------------------------------
// gate v3: 64x256 tile, A=[C|W] fully LDS-resident (64 KB), BK=32 B-staging
// (16 KB) -> 80 KB dynamic LDS, 2 blocks/CU. Epilogue reads C/W from LDS.
// 512 threads = 8 waves (2x4), wave tile 32x64.
// ---------------------------------------------------------------------------
__global__ __launch_bounds__(512) void gate_gemm_v3(const unsigned short* __restrict__ Cbf,
                                                    const unsigned short* __restrict__ Wbf,
                                                    const unsigned short* __restrict__ WgT,
                                                    const float* __restrict__ bg,
                                                    float* __restrict__ Out) {
    extern __shared__ __align__(16) short glds[];
    short* Alds = glds;            // 64 rows x 512 shorts = 64 KB ([row][k])
    short* Bs   = glds + 32768;    // 256 cols x 32 shorts = 16 KB

    const int tid  = threadIdx.x;
    const int lane = tid & 63;
    const int wid  = tid >> 6;
    const int wr   = wid >> 2, wc = wid & 3;   // 2 x 4
    const int l15  = lane & 15, lg = lane >> 4;
    const int brow = blockIdx.x * 64;

    // stage A once: [row][0:256]=Cbf row, [row][256:512]=Wbf row (8 x 16B/thread)
#pragma unroll
    for (int is = 0; is < 8; ++is) {
        int off = is * 8192 + tid * 16;        // byte offset in 64 KB
        int row = off >> 10;                   // 1024 B per row
        int cs  = (off & 1023) >> 1;           // short col 0..511
        const unsigned short* src = (cs < 256)
            ? (Cbf + (size_t)(brow + row) * D_GNN + cs)
            : (Wbf + (size_t)(brow + row) * D_GNN + (cs - 256));
        gload16(src, Alds + (off >> 1));
    }

    f32x4 acc[2][4] = {};
    for (int kc = 0; kc < 16; ++kc) {
        // stage B chunk: WgT[col][kc*32..+32], 16 KB (2 x 16B/thread)
#pragma unroll
        for (int is = 0; is < 2; ++is) {
            int off = is * 8192 + tid * 16;    // bytes in 16 KB
            int col = off >> 6;                // 64 B per col
            int cs  = (off & 63) >> 1;
            gload16(WgT + (size_t)col * 512 + kc * 32 + cs, Bs + (off >> 1));
        }
        __syncthreads();
        bf16x8 af[2], bq[4];
#pragma unroll
        for (int m = 0; m < 2; ++m)
            af[m] = *(const bf16x8*)&Alds[(wr * 32 + m * 16 + l15) * 512 + kc * 32 + lg * 8];
#pragma unroll
        for (int n = 0; n < 4; ++n)
            bq[n] = *(const bf16x8*)&Bs[(wc * 64 + n * 16 + l15) * 32 + lg * 8];
#pragma unroll
        for (int m = 0; m < 2; ++m)
#pragma unroll
            for (int n = 0; n < 4; ++n)
                acc[m][n] = __builtin_amdgcn_mfma_f32_16x16x32_bf16(af[m], bq[n], acc[m][n], 0, 0, 0);
        __syncthreads();
    }

#pragma unroll
    for (int m = 0; m < 2; ++m) {
        int row0 = wr * 32 + m * 16 + lg * 4;
#pragma unroll
        for (int n = 0; n < 4; ++n) {
            int col = wc * 64 + n * 16 + l15;
            float bgc = bg[col];
#pragma unroll
            for (int r = 0; r < 4; ++r) {
                int rw = row0 + r;
                float g  = 1.f / (1.f + expf(-(acc[m][n][r] + bgc)));
                float cv = bf2f((unsigned short)Alds[rw * 512 + col]);
                float wv = bf2f((unsigned short)Alds[rw * 512 + 256 + col]);
                Out[(size_t)(brow + rw) * D_GNN + col] = fmaf(g, cv - wv, wv);
            }
        }
    }
}

// ---------------------------------------------------------------------------
extern "C" void kernel_launch(void* const* d_in, const int* in_sizes, int n_in,
                              void* d_out, int out_size, void* d_ws, size_t ws_size,
                              hipStream_t stream) {
    const float* center = (const float*)d_in[0];
    const float* allE   = (const float*)d_in[1];
    const int*   nidx   = (const int*)d_in[2];
    const float* nw     = (const float*)d_in[3];
    const float* Wq     = (const float*)d_in[4];
    const float* Wk     = (const float*)d_in[5];
    const float* Wg     = (const float*)d_in[6];
    const float* bg     = (const float*)d_in[7];
    float* out = (float*)d_out;

    // ws layout (bf16): Cbf | PW | allEbf | Mt | WgT  (~119 MB)
    unsigned short* Cbf    = (unsigned short*)d_ws;
    unsigned short* PW     = Cbf + (size_t)NROWS * D_GNN;
    unsigned short* allEbf = PW + (size_t)NROWS * D_GNN;
    unsigned short* Mt     = allEbf + (size_t)NNODES * D_GNN;
    unsigned short* WgT    = Mt + D_GNN * D_GNN;

    (void)hipFuncSetAttribute((const void*)gate_gemm_v3,
                              hipFuncAttributeMaxDynamicSharedMemorySize, 81920);

    prep         <<<dim3(CONV_BLOCKS + D_GNN + 512), dim3(256), 0, stream>>>(
        allE, allEbf, Wq, Wk, Mt, Wg, WgT);
    gemm_P_fused <<<dim3(NROWS / 128), dim3(512), 0,     stream>>>(center, Mt, Cbf, PW);
    gather_attn  <<<dim3(NROWS / 8),   dim3(256), 0,     stream>>>(PW, allEbf, nidx, nw);
    gate_gemm_v3 <<<dim3(NROWS / 64),  dim3(512), 81920, stream>>>(Cbf, PW, WgT, bg, out);
}

// Round 10
// 190.483 us; speedup vs baseline: 1.1175x; 1.1175x over previous
//
#include <hip/hip_runtime.h>
#include <math.h>

#define D_GNN 256
#define ATTN  64
#define KNEI  16
#define NROWS 65536
#define NNODES 100000

constexpr float EPSV  = 1e-6f;
constexpr float SCALE = 0.125f;   // 64^-0.5

typedef __attribute__((ext_vector_type(8))) short bf16x8;
typedef __attribute__((ext_vector_type(4))) float f32x4;

__device__ __forceinline__ unsigned short f2bf(float f) {
    union { float f; unsigned u; } v; v.f = f;
    return (unsigned short)((v.u + 0x7FFFu + ((v.u >> 16) & 1u)) >> 16);
}
__device__ __forceinline__ float bf2f(unsigned short h) {
    union { unsigned u; float f; } v; v.u = ((unsigned)h) << 16;
    return v.f;
}

typedef __attribute__((address_space(3))) short lds_short;
typedef __attribute__((address_space(1))) const short gm_short;
__device__ __forceinline__ void gload16(const unsigned short* g, short* l) {
    __builtin_amdgcn_global_load_lds((gm_short*)g, (lds_short*)l, 16, 0, 0);
}

// ---------------------------------------------------------------------------
// prep_small: blocks [0,256): Mt row; [256,768): WgT column.
// Mt[j][i] = (Wq @ Wk^T)[i][j] bf16;  WgT[j][k] = Wg[k][j] bf16.
// ---------------------------------------------------------------------------
__global__ __launch_bounds__(256) void prep_small(const float* __restrict__ Wq,
                                                  const float* __restrict__ Wk,
                                                  unsigned short* __restrict__ Mt,
                                                  const float* __restrict__ Wg,
                                                  unsigned short* __restrict__ WgT) {
    __shared__ float wq[ATTN];
    int bid = blockIdx.x;
    int j   = threadIdx.x;
    if (bid < D_GNN) {
        int i = bid;
        if (j < ATTN) wq[j] = Wq[i * ATTN + j];
        __syncthreads();
        float s = 0.f;
#pragma unroll
        for (int a = 0; a < ATTN; ++a) s = fmaf(wq[a], Wk[j * ATTN + a], s);
        Mt[j * D_GNN + i] = f2bf(s);
    } else {
        int k = bid - D_GNN;    // 0..511
        WgT[j * 512 + k] = f2bf(Wg[k * D_GNN + j]);
    }
}

// ---------------------------------------------------------------------------
// Merged: blocks [0,512): gemm_P (Cbf side-product + P = Cbf @ Mt^T);
//         blocks [512,13012): allE fp32->bf16 conversion (2048 floats/block).
// Independent work co-scheduled to fill BW bubbles; one launch.
// ---------------------------------------------------------------------------
#define GEMM_BLOCKS 512
#define CONV_BLOCKS (NNODES * D_GNN / 2048)   // 12500
__global__ __launch_bounds__(512) void conv_gemmP(const float* __restrict__ allE,
                                                  unsigned short* __restrict__ allEbf,
                                                  const float* __restrict__ C32,
                                                  const unsigned short* __restrict__ Mt,
                                                  unsigned short* __restrict__ Cbf,
                                                  unsigned short* __restrict__ Pbf) {
    __shared__ short As[128 * 64];   // 16 KB
    __shared__ short Bs[256 * 64];   // 32 KB
    const int bid = blockIdx.x;
    const int tid = threadIdx.x;

    if (bid >= GEMM_BLOCKS) {
        // ---- conv role: one float4 per thread ----
        size_t i = ((size_t)(bid - GEMM_BLOCKS) * 512 + tid) * 4;
        float4 v = *(const float4*)(allE + i);
        short4 o;
        o.x = (short)f2bf(v.x); o.y = (short)f2bf(v.y);
        o.z = (short)f2bf(v.z); o.w = (short)f2bf(v.w);
        *(short4*)(allEbf + i) = o;
        return;
    }

    // ---- gemm role: 128x256 tile, BK=64, 8 waves (2x4), wave tile 64x64 ----
    const int lane = tid & 63;
    const int wid  = tid >> 6;
    const int wr   = wid >> 2, wc = wid & 3;
    const int l15  = lane & 15, lg = lane >> 4;
    const int brow = bid * 128;

    f32x4 acc[4][4] = {};

    for (int k0 = 0; k0 < D_GNN; k0 += 64) {
#pragma unroll
        for (int is = 0; is < 4; ++is) {
            int off  = is * 8192 + tid * 16;
            int row  = off >> 7;
            int cs   = (off & 127) >> 1;
            int lofs = is * 4096 + wid * 512;
            gload16(Mt + (size_t)row * D_GNN + k0 + cs, Bs + lofs);
        }
#pragma unroll
        for (int is = 0; is < 2; ++is) {
            int offsh = is * 4096 + tid * 8;
            int row   = offsh >> 6;
            int col   = offsh & 63;
            size_t gp = (size_t)(brow + row) * D_GNN + k0 + col;
            float4 v0 = *(const float4*)(C32 + gp);
            float4 v1 = *(const float4*)(C32 + gp + 4);
            bf16x8 h;
            h[0] = (short)f2bf(v0.x); h[1] = (short)f2bf(v0.y);
            h[2] = (short)f2bf(v0.z); h[3] = (short)f2bf(v0.w);
            h[4] = (short)f2bf(v1.x); h[5] = (short)f2bf(v1.y);
            h[6] = (short)f2bf(v1.z); h[7] = (short)f2bf(v1.w);
            *(bf16x8*)&As[offsh] = h;
            *(bf16x8*)(Cbf + gp) = h;
        }
        __syncthreads();
#pragma unroll
        for (int kk = 0; kk < 64; kk += 32) {
            bf16x8 af[4], bq[4];
#pragma unroll
            for (int m = 0; m < 4; ++m)
                af[m] = *(const bf16x8*)&As[(wr * 64 + m * 16 + l15) * 64 + kk + lg * 8];
#pragma unroll
            for (int n = 0; n < 4; ++n)
                bq[n] = *(const bf16x8*)&Bs[(wc * 64 + n * 16 + l15) * 64 + kk + lg * 8];
#pragma unroll
            for (int m = 0; m < 4; ++m)
#pragma unroll
                for (int n = 0; n < 4; ++n)
                    acc[m][n] = __builtin_amdgcn_mfma_f32_16x16x32_bf16(af[m], bq[n], acc[m][n], 0, 0, 0);
        }
        __syncthreads();
    }
#pragma unroll
    for (int m = 0; m < 4; ++m) {
        int row0 = brow + wr * 64 + m * 16 + lg * 4;
#pragma unroll
        for (int n = 0; n < 4; ++n) {
            int col = wc * 64 + n * 16 + l15;
#pragma unroll
            for (int r = 0; r < 4; ++r)
                Pbf[(size_t)(row0 + r) * D_GNN + col] = f2bf(acc[m][n][r]);
        }
    }
}

// ---------------------------------------------------------------------------
// gather(LDS-staged) + scores + softmax + weighted sum, bf16. (R7, untouched)
// ---------------------------------------------------------------------------
__global__ __launch_bounds__(256) void gather_attn(unsigned short* __restrict__ PW,
                                                   const unsigned short* __restrict__ allEbf,
                                                   const int* __restrict__ nidx,
                                                   const float* __restrict__ nw) {
    __shared__ short stage[4][KNEI * 512];   // 16KB per wave, 64KB total

    int lane = threadIdx.x & 63;
    int wid  = threadIdx.x >> 6;
    int half = lane >> 5;
    int hl   = lane & 31;
    int b    = blockIdx.x * 8 + wid * 2 + half;

#pragma unroll
    for (int t = 0; t < KNEI; ++t) {
        int idx = nidx[b * KNEI + t];
        gload16(allEbf + (size_t)idx * D_GNN + hl * 8, &stage[wid][t * 512]);
    }

    bf16x8 pq = ((const bf16x8*)(PW + (size_t)b * D_GNN))[hl];
    float p[8];
#pragma unroll
    for (int j = 0; j < 8; ++j) p[j] = bf2f((unsigned short)pq[j]);

    __syncthreads();

    float sc[KNEI];
#pragma unroll
    for (int k = 0; k < KNEI; ++k) {
        bf16x8 v = *(const bf16x8*)&stage[wid][k * 512 + half * 256 + hl * 8];
        float s = 0.f;
#pragma unroll
        for (int j = 0; j < 8; ++j) s = fmaf(bf2f((unsigned short)v[j]), p[j], s);
        sc[k] = s;
    }

    float t8[8];
#pragma unroll
    for (int j = 0; j < 8; ++j) {
        float send = (hl & 16) ? sc[j] : sc[j + 8];
        float keep = (hl & 16) ? sc[j + 8] : sc[j];
        t8[j] = keep + __shfl_xor(send, 16);
    }
    float t4[4];
#pragma unroll
    for (int j = 0; j < 4; ++j) {
        float send = (hl & 1) ? t8[j] : t8[j + 4];
        float keep = (hl & 1) ? t8[j + 4] : t8[j];
        t4[j] = keep + __shfl_xor(send, 1);
    }
    float t2[2];
#pragma unroll
    for (int j = 0; j < 2; ++j) {
        float send = (hl & 2) ? t4[j] : t4[j + 2];
        float keep = (hl & 2) ? t4[j + 2] : t4[j];
        t2[j] = keep + __shfl_xor(send, 2);
    }
    float s1;
    {
        float send = (hl & 4) ? t2[0] : t2[1];
        float keep = (hl & 4) ? t2[1] : t2[0];
        s1 = keep + __shfl_xor(send, 4);
    }
    s1 += __shfl_xor(s1, 8);
    int kidx = ((hl >> 4) & 1) * 8 + (hl & 1) * 4 + ((hl >> 1) & 1) * 2 + ((hl >> 2) & 1);

    float w = nw[b * KNEI + kidx];
    float s = (w < EPSV) ? -INFINITY : fmaf(s1, SCALE, logf(w));

    float mx = s;
    mx = fmaxf(mx, __shfl_xor(mx, 16));
    mx = fmaxf(mx, __shfl_xor(mx, 1));
    mx = fmaxf(mx, __shfl_xor(mx, 2));
    mx = fmaxf(mx, __shfl_xor(mx, 4));
    float e = (mx > -INFINITY) ? expf(s - mx) : 0.f;
    float den = e;
    den += __shfl_xor(den, 16);
    den += __shfl_xor(den, 1);
    den += __shfl_xor(den, 2);
    den += __shfl_xor(den, 4);
    float a = (mx > -INFINITY) ? e / den : 0.f;

    float acc[8] = {};
#pragma unroll
    for (int k = 0; k < KNEI; ++k) {
        int sl = (((k >> 3) & 1) << 4) | ((k >> 2) & 1) | (((k >> 1) & 1) << 1) | ((k & 1) << 2);
        float ak = __shfl(a, sl, 32);
        bf16x8 v = *(const bf16x8*)&stage[wid][k * 512 + half * 256 + hl * 8];
#pragma unroll
        for (int j = 0; j < 8; ++j)
            acc[j] = fmaf(ak, bf2f((unsigned short)v[j]), acc[j]);
    }

    bf16x8 o;
#pragma unroll
    for (int j = 0; j < 8; ++j) o[j] = (short)f2bf(acc[j]);
    ((bf16x8*)(PW + (size_t)b * D_GNN))[hl] = o;
}

// ---------------------------------------------------------------------------
// gate (R7, untouched): 128x256 tile, A staged once per row, K=512.
// 512 threads = 8 waves (2x4).
// ---------------------------------------------------------------------------
__global__ __launch_bounds__(512) void gate_gemm_mfma(const unsigned short* __restrict__ Cbf,
                                                      const unsigned short* __restrict__ Wbf,
                                                      const unsigned short* __restrict__ WgT,
                                                      const float* __restrict__ bg,
                                                      float* __restrict__ Out) {
    __shared__ short As[128 * 64];   // 16 KB
    __shared__ short Bs[256 * 64];   // 32 KB
    const int tid  = threadIdx.x;
    const int lane = tid & 63;
    const int wid  = tid >> 6;
    const int wr   = wid >> 2, wc = wid & 3;
    const int l15  = lane & 15, lg = lane >> 4;
    const int brow = blockIdx.x * 128;

    f32x4 acc[4][4] = {};

    for (int k0 = 0; k0 < 2 * D_GNN; k0 += 64) {
        const unsigned short* Asrc = (k0 < D_GNN) ? Cbf : Wbf;
        int koff = k0 & (D_GNN - 1);
#pragma unroll
        for (int is = 0; is < 2; ++is) {
            int off  = is * 8192 + tid * 16;
            int row  = off >> 7;
            int cs   = (off & 127) >> 1;
            int lofs = is * 4096 + wid * 512;
            gload16(Asrc + (size_t)(brow + row) * D_GNN + koff + cs, As + lofs);
        }
#pragma unroll
        for (int is = 0; is < 4; ++is) {
            int off  = is * 8192 + tid * 16;
            int row  = off >> 7;
            int cs   = (off & 127) >> 1;
            int lofs = is * 4096 + wid * 512;
            gload16(WgT + (size_t)row * 512 + k0 + cs, Bs + lofs);
        }
        __syncthreads();
#pragma unroll
        for (int kk = 0; kk < 64; kk += 32) {
            bf16x8 af[4], bq[4];
#pragma unroll
            for (int m = 0; m < 4; ++m)
                af[m] = *(const bf16x8*)&As[(wr * 64 + m * 16 + l15) * 64 + kk + lg * 8];
#pragma unroll
            for (int n = 0; n < 4; ++n)
                bq[n] = *(const bf16x8*)&Bs[(wc * 64 + n * 16 + l15) * 64 + kk + lg * 8];
#pragma unroll
            for (int m = 0; m < 4; ++m)
#pragma unroll
                for (int n = 0; n < 4; ++n)
                    acc[m][n] = __builtin_amdgcn_mfma_f32_16x16x32_bf16(af[m], bq[n], acc[m][n], 0, 0, 0);
        }
        __syncthreads();
    }
#pragma unroll
    for (int m = 0; m < 4; ++m) {
        int row0 = brow + wr * 64 + m * 16 + lg * 4;
#pragma unroll
        for (int n = 0; n < 4; ++n) {
            int col = wc * 64 + n * 16 + l15;
            float bgc = bg[col];
#pragma unroll
            for (int r = 0; r < 4; ++r) {
                size_t rr = (size_t)(row0 + r);
                float g  = 1.f / (1.f + expf(-(acc[m][n][r] + bgc)));
                float cv = bf2f(Cbf[rr * D_GNN + col]);
                float wv = bf2f(Wbf[rr * D_GNN + col]);
                Out[rr * D_GNN + col] = fmaf(g, cv - wv, wv);
            }
        }
    }
}

// ---------------------------------------------------------------------------
extern "C" void kernel_launch(void* const* d_in, const int* in_sizes, int n_in,
                              void* d_out, int out_size, void* d_ws, size_t ws_size,
                              hipStream_t stream) {
    const float* center = (const float*)d_in[0];
    const float* allE   = (const float*)d_in[1];
    const int*   nidx   = (const int*)d_in[2];
    const float* nw     = (const float*)d_in[3];
    const float* Wq     = (const float*)d_in[4];
    const float* Wk     = (const float*)d_in[5];
    const float* Wg     = (const float*)d_in[6];
    const float* bg     = (const float*)d_in[7];
    float* out = (float*)d_out;

    // ws layout (bf16): Cbf | PW | allEbf | Mt | WgT  (~119 MB)
    unsigned short* Cbf    = (unsigned short*)d_ws;
    unsigned short* PW     = Cbf + (size_t)NROWS * D_GNN;
    unsigned short* allEbf = PW + (size_t)NROWS * D_GNN;
    unsigned short* Mt     = allEbf + (size_t)NNODES * D_GNN;
    unsigned short* WgT    = Mt + D_GNN * D_GNN;

    prep_small    <<<dim3(D_GNN + 512),               dim3(256), 0, stream>>>(Wq, Wk, Mt, Wg, WgT);
    conv_gemmP    <<<dim3(GEMM_BLOCKS + CONV_BLOCKS), dim3(512), 0, stream>>>(
        allE, allEbf, center, Mt, Cbf, PW);
    gather_attn   <<<dim3(NROWS / 8),                 dim3(256), 0, stream>>>(PW, allEbf, nidx, nw);
    gate_gemm_mfma<<<dim3(NROWS / 128),               dim3(512), 0, stream>>>(Cbf, PW, WgT, bg, out);
}